// Round 4
// baseline (459.093 us; speedup 1.0000x reference)
//
#include <hip/hip_runtime.h>

#define NN 2048
#define NN2 (NN * NN)

// ---- vector load helpers: 4 points per thread, j0 = 4*jt (16B aligned) ----
__device__ __forceinline__ void load6z(const float* __restrict__ A, int i, int j0, float a[6]) {
    if ((unsigned)i >= (unsigned)NN) {
#pragma unroll
        for (int q = 0; q < 6; ++q) a[q] = 0.f;
        return;
    }
    const float* row = A + (size_t)i * NN;
    float4 c = *reinterpret_cast<const float4*>(row + j0);
    a[1] = c.x; a[2] = c.y; a[3] = c.z; a[4] = c.w;
    a[0] = (j0 > 0) ? row[j0 - 1] : 0.f;
    a[5] = (j0 + 4 < NN) ? row[j0 + 4] : 0.f;
}
__device__ __forceinline__ void load4z(const float* __restrict__ A, int i, int j0, float a[4]) {
    if ((unsigned)i >= (unsigned)NN) {
#pragma unroll
        for (int q = 0; q < 4; ++q) a[q] = 0.f;
        return;
    }
    float4 c = *reinterpret_cast<const float4*>(A + (size_t)i * NN + j0);
    a[0] = c.x; a[1] = c.y; a[2] = c.z; a[3] = c.w;
}
__device__ __forceinline__ void load6e(const float* __restrict__ A, int i, int j0, float a[6]) {
    i = i < 0 ? 0 : (i > NN - 1 ? NN - 1 : i);
    const float* row = A + (size_t)i * NN;
    float4 c = *reinterpret_cast<const float4*>(row + j0);
    a[1] = c.x; a[2] = c.y; a[3] = c.z; a[4] = c.w;
    a[0] = (j0 > 0) ? row[j0 - 1] : c.x;
    a[5] = (j0 + 4 < NN) ? row[j0 + 4] : c.w;
}
__device__ __forceinline__ void load4e(const float* __restrict__ A, int i, int j0, float a[4]) {
    i = i < 0 ? 0 : (i > NN - 1 ? NN - 1 : i);
    float4 c = *reinterpret_cast<const float4*>(A + (size_t)i * NN + j0);
    a[0] = c.x; a[1] = c.y; a[2] = c.z; a[3] = c.w;
}
__device__ __forceinline__ void store4(float* __restrict__ A, int i, int j0, const float a[4]) {
    *reinterpret_cast<float4*>(A + (size_t)i * NN + j0) = make_float4(a[0], a[1], a[2], a[3]);
}

// ===================== fused pg1 + predictor =====================
__global__ __launch_bounds__(256) void k_pred_f(const float* __restrict__ u, const float* __restrict__ v,
                                                const float* __restrict__ k1, const float* __restrict__ p,
                                                float* __restrict__ bu, float* __restrict__ bv) {
    const float DT = 0.01f;
    __shared__ __align__(16) float su[36][72], sv[36][72];
    __shared__ float sku[34][68], skv[34][68];
    const int jb = blockIdx.x * 64;
    const int ib = blockIdx.y * 32;
    const int tid = threadIdx.y * 16 + threadIdx.x;

    for (int idx = tid; idx < 36 * 18; idx += 256) {
        int r = idx / 18, c4 = idx - r * 18;
        int gi = ib - 2 + r;
        int gj = jb - 4 + c4 * 4;
        float4 uu = make_float4(0.f, 0.f, 0.f, 0.f), vv = uu;
        if ((unsigned)gi < (unsigned)NN) {
            if (gj >= 0 && gj + 3 < NN) {
                uu = *reinterpret_cast<const float4*>(u + (size_t)gi * NN + gj);
                vv = *reinterpret_cast<const float4*>(v + (size_t)gi * NN + gj);
            } else {
                float tu[4], tv[4];
#pragma unroll
                for (int q = 0; q < 4; ++q) {
                    int g = gj + q;
                    bool in = (unsigned)g < (unsigned)NN;
                    tu[q] = in ? u[(size_t)gi * NN + g] : 0.f;
                    tv[q] = in ? v[(size_t)gi * NN + g] : 0.f;
                }
                uu = make_float4(tu[0], tu[1], tu[2], tu[3]);
                vv = make_float4(tv[0], tv[1], tv[2], tv[3]);
            }
        }
        *reinterpret_cast<float4*>(&su[r][c4 * 4]) = uu;
        *reinterpret_cast<float4*>(&sv[r][c4 * 4]) = vv;
    }
    __syncthreads();

    for (int idx = tid; idx < 34 * 66; idx += 256) {
        int r = idx / 66, c = idx - r * 66;
        int gi = ib - 1 + r, gj = jb - 1 + c;
        float kuo = 0.f, kvo = 0.f;
        if ((unsigned)gi < (unsigned)NN && (unsigned)gj < (unsigned)NN) {
            int lr = r + 1, lc = c + 3;
            float uc = su[lr][lc], ul = su[lr][lc - 1], ur = su[lr][lc + 1], ut = su[lr - 1][lc], ub = su[lr + 1][lc];
            float vc = sv[lr][lc], vl = sv[lr][lc - 1], vr = sv[lr][lc + 1], vt = sv[lr - 1][lc], vb = sv[lr + 1][lc];
            float ADxu = 0.5f * (ur - ul), ADyu = 0.5f * (ub - ut);
            float ADxv = 0.5f * (vr - vl), ADyv = 0.5f * (vb - vt);
            float Lu = ul + ur + ut + ub - 4.f * uc;
            float Lv = vl + vr + vt + vb - 4.f * vc;
            float s = fabsf(uc) + fabsf(vc);
            float kuv = 0.25f * fabsf(0.5f * s * Lu) / (0.001f + 0.5f * (fabsf(ADxu) + fabsf(ADyu)));
            float kvv = 0.25f * fabsf(0.5f * s * Lv) / (0.001f + 0.5f * (fabsf(ADxv) + fabsf(ADyv)));
            float k1c = k1[(size_t)gi * NN + gj];
            kuo = fminf(kuv, k1c);
            kvo = fminf(kvv, k1c);
        }
        sku[r][c] = kuo;
        skv[r][c] = kvo;
    }
    __syncthreads();

    const int i0 = ib + threadIdx.y * 2;
    const int j0 = jb + threadIdx.x * 4;
#pragma unroll
    for (int a = 0; a < 2; ++a) {
        int i = i0 + a;
        float p6[6], pu[4], pd[4], obu[4], obv[4];
        load6e(p, i, j0, p6); load4e(p, i - 1, j0, pu); load4e(p, i + 1, j0, pd);
        int lur = i - ib + 2, lkr = i - ib + 1;
#pragma unroll
        for (int c = 0; c < 4; ++c) {
            int luc = j0 + c - jb + 4, lkc = j0 + c - jb + 1;
            float uc = su[lur][luc], ul = su[lur][luc - 1], ur = su[lur][luc + 1], ut = su[lur - 1][luc], ub = su[lur + 1][luc];
            float vc = sv[lur][luc], vl = sv[lur][luc - 1], vr = sv[lur][luc + 1], vt = sv[lur - 1][luc], vb = sv[lur + 1][luc];
            float kuc = sku[lkr][lkc], kul = sku[lkr][lkc - 1], kur = sku[lkr][lkc + 1], kut = sku[lkr - 1][lkc], kub = sku[lkr + 1][lkc];
            float kvc = skv[lkr][lkc], kvl = skv[lkr][lkc - 1], kvr = skv[lkr][lkc + 1], kvt = skv[lkr - 1][lkc], kvb = skv[lkr + 1][lkc];
            float ADxu = 0.5f * (ur - ul), ADyu = 0.5f * (ub - ut);
            float ADxv = 0.5f * (vr - vl), ADyv = 0.5f * (vb - vt);
            float Lu = ul + ur + ut + ub - 4.f * uc;
            float Lv = vl + vr + vt + vb - 4.f * vc;
            float Lku = kul + kur + kut + kub - 4.f * kuc;
            float Lkv = kvl + kvr + kvt + kvb - 4.f * kvc;
            float Luku = ul * kul + ur * kur + ut * kut + ub * kub - 4.f * uc * kuc;
            float Lvkv = vl * kvl + vr * kvr + vt * kvt + vb * kvb - 4.f * vc * kvc;
            float kx = 1.5f * (kuc * Lu + Luku - uc * Lku);
            float ky = 1.5f * (kvc * Lv + Lvkv - vc * Lkv);
            float Grapx = 0.5f * (p6[c + 2] - p6[c]) * DT;
            float Grapy = 0.5f * (pd[c] - pu[c]) * DT;
            obu[c] = uc + 0.5f * (kx * DT - uc * ADxu * DT - vc * ADyu * DT) - Grapx;
            obv[c] = vc + 0.5f * (ky * DT - uc * ADxv * DT - vc * ADyv * DT) - Grapy;
        }
        store4(bu, i, j0, obu);
        store4(bv, i, j0, obv);
    }
}

// ===================== fused pg1(b) + corrector =====================
__global__ __launch_bounds__(256) void k_corr_f(const float* __restrict__ u, const float* __restrict__ v,
                                                const float* __restrict__ k1, const float* __restrict__ p,
                                                const float* __restrict__ bu, const float* __restrict__ bv,
                                                const float* __restrict__ Fx, const float* __restrict__ Fy,
                                                float* __restrict__ un, float* __restrict__ vn) {
    const float DT = 0.01f;
    __shared__ __align__(16) float sbu[36][72], sbv[36][72];
    __shared__ float sku[34][68], skv[34][68];
    const int jb = blockIdx.x * 64;
    const int ib = blockIdx.y * 32;
    const int tid = threadIdx.y * 16 + threadIdx.x;

    for (int idx = tid; idx < 36 * 18; idx += 256) {
        int r = idx / 18, c4 = idx - r * 18;
        int gi = ib - 2 + r;
        int gj = jb - 4 + c4 * 4;
        float4 uu = make_float4(0.f, 0.f, 0.f, 0.f), vv = uu;
        if ((unsigned)gi < (unsigned)NN) {
            if (gj >= 0 && gj + 3 < NN) {
                uu = *reinterpret_cast<const float4*>(bu + (size_t)gi * NN + gj);
                vv = *reinterpret_cast<const float4*>(bv + (size_t)gi * NN + gj);
            } else {
                float tu[4], tv[4];
#pragma unroll
                for (int q = 0; q < 4; ++q) {
                    int g = gj + q;
                    bool in = (unsigned)g < (unsigned)NN;
                    tu[q] = in ? bu[(size_t)gi * NN + g] : 0.f;
                    tv[q] = in ? bv[(size_t)gi * NN + g] : 0.f;
                }
                uu = make_float4(tu[0], tu[1], tu[2], tu[3]);
                vv = make_float4(tv[0], tv[1], tv[2], tv[3]);
            }
        }
        *reinterpret_cast<float4*>(&sbu[r][c4 * 4]) = uu;
        *reinterpret_cast<float4*>(&sbv[r][c4 * 4]) = vv;
    }
    __syncthreads();

    for (int idx = tid; idx < 34 * 66; idx += 256) {
        int r = idx / 66, c = idx - r * 66;
        int gi = ib - 1 + r, gj = jb - 1 + c;
        float kuo = 0.f, kvo = 0.f;
        if ((unsigned)gi < (unsigned)NN && (unsigned)gj < (unsigned)NN) {
            int lr = r + 1, lc = c + 3;
            float uc = sbu[lr][lc], ul = sbu[lr][lc - 1], ur = sbu[lr][lc + 1], ut = sbu[lr - 1][lc], ub = sbu[lr + 1][lc];
            float vc = sbv[lr][lc], vl = sbv[lr][lc - 1], vr = sbv[lr][lc + 1], vt = sbv[lr - 1][lc], vb = sbv[lr + 1][lc];
            float ADxu = 0.5f * (ur - ul), ADyu = 0.5f * (ub - ut);
            float ADxv = 0.5f * (vr - vl), ADyv = 0.5f * (vb - vt);
            float Lu = ul + ur + ut + ub - 4.f * uc;
            float Lv = vl + vr + vt + vb - 4.f * vc;
            float s = fabsf(uc) + fabsf(vc);
            float kuv = 0.25f * fabsf(0.5f * s * Lu) / (0.001f + 0.5f * (fabsf(ADxu) + fabsf(ADyu)));
            float kvv = 0.25f * fabsf(0.5f * s * Lv) / (0.001f + 0.5f * (fabsf(ADxv) + fabsf(ADyv)));
            float k1c = k1[(size_t)gi * NN + gj];
            kuo = fminf(kuv, k1c);
            kvo = fminf(kvv, k1c);
        }
        sku[r][c] = kuo;
        skv[r][c] = kvo;
    }
    __syncthreads();

    const int i0 = ib + threadIdx.y * 2;
    const int j0 = jb + threadIdx.x * 4;
#pragma unroll
    for (int a = 0; a < 2; ++a) {
        int i = i0 + a;
        float p6[6], pu[4], pd[4];
        float u6[6], uu[4], ud[4], v6[6], vu[4], vd[4], fx[4], fy[4], oun[4], ovn[4];
        load6e(p, i, j0, p6); load4e(p, i - 1, j0, pu); load4e(p, i + 1, j0, pd);
        load6z(u, i, j0, u6); load4z(u, i - 1, j0, uu); load4z(u, i + 1, j0, ud);
        load6z(v, i, j0, v6); load4z(v, i - 1, j0, vu); load4z(v, i + 1, j0, vd);
        load4z(Fx, i, j0, fx); load4z(Fy, i, j0, fy);
        int lbr = i - ib + 2, lkr = i - ib + 1;
#pragma unroll
        for (int c = 0; c < 4; ++c) {
            int lbc = j0 + c - jb + 4, lkc = j0 + c - jb + 1;
            float buc = sbu[lbr][lbc], bul = sbu[lbr][lbc - 1], bur = sbu[lbr][lbc + 1], but = sbu[lbr - 1][lbc], bub = sbu[lbr + 1][lbc];
            float bvc = sbv[lbr][lbc], bvl = sbv[lbr][lbc - 1], bvr = sbv[lbr][lbc + 1], bvt = sbv[lbr - 1][lbc], bvb = sbv[lbr + 1][lbc];
            float kuc = sku[lkr][lkc], kul = sku[lkr][lkc - 1], kur = sku[lkr][lkc + 1], kut = sku[lkr - 1][lkc], kub = sku[lkr + 1][lkc];
            float kvc = skv[lkr][lkc], kvl = skv[lkr][lkc - 1], kvr = skv[lkr][lkc + 1], kvt = skv[lkr - 1][lkc], kvb = skv[lkr + 1][lkc];
            float uc = u6[c + 1], ul = u6[c], ur = u6[c + 2], ut = uu[c], ub = ud[c];
            float vc = v6[c + 1], vl = v6[c], vr = v6[c + 2], vt = vu[c], vb = vd[c];
            float ADxbu = 0.5f * (bur - bul), ADybu = 0.5f * (bub - but);
            float ADxbv = 0.5f * (bvr - bvl), ADybv = 0.5f * (bvb - bvt);
            float Lbu = bul + bur + but + bub - 4.f * buc;
            float Lbv = bvl + bvr + bvt + bvb - 4.f * bvc;
            float Lku = kul + kur + kut + kub - 4.f * kuc;
            float Lkv = kvl + kvr + kvt + kvb - 4.f * kvc;
            float Luku = ul * kul + ur * kur + ut * kut + ub * kub - 4.f * uc * kuc;
            float Lvkv = vl * kvl + vr * kvr + vt * kvt + vb * kvb - 4.f * vc * kvc;
            float kx = 1.5f * (kuc * Lbu + Luku - buc * Lku);
            float ky = 1.5f * (kvc * Lbv + Lvkv - bvc * Lkv);
            float Grapx = 0.5f * (p6[c + 2] - p6[c]) * DT;
            float Grapy = 0.5f * (pd[c] - pu[c]) * DT;
            oun[c] = uc + kx * DT - buc * ADxbu * DT - bvc * ADybu * DT - Grapx - fx[c] * DT;
            ovn[c] = vc + ky * DT - buc * ADxbv * DT - bvc * ADybv * DT - Grapy - fy[c] * DT;
        }
        store4(un, i, j0, oun);
        store4(vn, i, j0, ovn);
    }
}

// -------- fused: b = -div(un,vn)/DT  +  residual(p,b)  +  restrict to 1024/512/256/128 --------
__global__ __launch_bounds__(256) void k_rhs_res(const float* __restrict__ un, const float* __restrict__ vn,
                                                 const float* __restrict__ p, float* __restrict__ b,
                                                 float* __restrict__ r1024, float* __restrict__ r512,
                                                 float* __restrict__ r256, float* __restrict__ r128) {
    __shared__ float s512r[4][64];
    __shared__ float s256r[2][32];
    int tx = threadIdx.x, ty = threadIdx.y;
    int jt = blockIdx.x * 64 + tx;   // [0,512)
    int it = blockIdx.y * 4 + ty;    // [0,512)
    int j0 = jt * 4, i0 = it * 4;
    // b tile (4x4)
    float bb[4][4];
#pragma unroll
    for (int r = 0; r < 4; ++r) {
        float u6[6], vu[4], vd[4];
        load6z(un, i0 + r, j0, u6);
        load4z(vn, i0 + r - 1, j0, vu);
        load4z(vn, i0 + r + 1, j0, vd);
#pragma unroll
        for (int c = 0; c < 4; ++c)
            bb[r][c] = -100.f * (0.5f * (u6[c + 2] - u6[c]) + 0.5f * (vd[c] - vu[c]));
        store4(b, i0 + r, j0, bb[r]);
    }
    // residual
    float p6[6][6];
#pragma unroll
    for (int r = 0; r < 6; ++r) load6e(p, i0 - 1 + r, j0, p6[r]);
    float res[4][4];
#pragma unroll
    for (int r = 0; r < 4; ++r)
#pragma unroll
        for (int c = 0; c < 4; ++c) {
            float pc = p6[r + 1][c + 1];
            res[r][c] = p6[r][c + 1] + p6[r + 2][c + 1] + p6[r + 1][c] + p6[r + 1][c + 2] - 4.f * pc - bb[r][c];
        }
    // restrict
    float q00 = 0.25f * (res[0][0] + res[0][1] + res[1][0] + res[1][1]);
    float q01 = 0.25f * (res[0][2] + res[0][3] + res[1][2] + res[1][3]);
    float q10 = 0.25f * (res[2][0] + res[2][1] + res[3][0] + res[3][1]);
    float q11 = 0.25f * (res[2][2] + res[2][3] + res[3][2] + res[3][3]);
    int ci = it * 2, cj = jt * 2;
    *reinterpret_cast<float2*>(r1024 + (size_t)ci * 1024 + cj)       = make_float2(q00, q01);
    *reinterpret_cast<float2*>(r1024 + (size_t)(ci + 1) * 1024 + cj) = make_float2(q10, q11);
    float s = 0.25f * (q00 + q01 + q10 + q11);
    r512[(size_t)it * 512 + jt] = s;
    s512r[ty][tx] = s;
    __syncthreads();
    int tid = ty * 64 + tx;
    if (tid < 64) {
        int a = tid >> 5, c = tid & 31;
        float m = 0.25f * (s512r[2 * a][2 * c] + s512r[2 * a][2 * c + 1] + s512r[2 * a + 1][2 * c] + s512r[2 * a + 1][2 * c + 1]);
        r256[(size_t)(blockIdx.y * 2 + a) * 256 + blockIdx.x * 32 + c] = m;
        s256r[a][c] = m;
    }
    __syncthreads();
    if (tid < 16) {
        float m = 0.25f * (s256r[0][2 * tid] + s256r[0][2 * tid + 1] + s256r[1][2 * tid] + s256r[1][2 * tid + 1]);
        r128[(size_t)blockIdx.y * 128 + blockIdx.x * 16 + tid] = m;
    }
}

// ---------------- all coarse levels (<=128) in one block ----------------
__global__ __launch_bounds__(1024) void k_small(const float* __restrict__ r128,
                                                float* __restrict__ w128_out,
                                                float* __restrict__ r2_out) {
    __shared__ float sr64[64 * 64];
    __shared__ float sr32[32 * 32];
    __shared__ float sr16[16 * 16];
    __shared__ float sr8[8 * 8];
    __shared__ float sr4[16];
    __shared__ float sr2[4];
    __shared__ float wa[64 * 64];
    __shared__ float wb[64 * 64];
    int t = threadIdx.x;

    for (int idx = t; idx < 64 * 64; idx += 1024) {
        int i = idx >> 6, j = idx & 63;
        const float* s0 = r128 + (2 * i) * 128 + 2 * j;
        sr64[idx] = 0.25f * (s0[0] + s0[1] + s0[128] + s0[129]);
    }
    __syncthreads();
    if (t < 32 * 32) {
        int i = t >> 5, j = t & 31;
        const float* s0 = sr64 + (2 * i) * 64 + 2 * j;
        sr32[t] = 0.25f * (s0[0] + s0[1] + s0[64] + s0[65]);
    }
    __syncthreads();
    if (t < 16 * 16) {
        int i = t >> 4, j = t & 15;
        const float* s0 = sr32 + (2 * i) * 32 + 2 * j;
        sr16[t] = 0.25f * (s0[0] + s0[1] + s0[32] + s0[33]);
    }
    __syncthreads();
    if (t < 64) {
        int i = t >> 3, j = t & 7;
        const float* s0 = sr16 + (2 * i) * 16 + 2 * j;
        sr8[t] = 0.25f * (s0[0] + s0[1] + s0[16] + s0[17]);
    }
    __syncthreads();
    if (t < 16) {
        int i = t >> 2, j = t & 3;
        const float* s0 = sr8 + (2 * i) * 8 + 2 * j;
        sr4[t] = 0.25f * (s0[0] + s0[1] + s0[8] + s0[9]);
    }
    __syncthreads();
    if (t < 4) {
        int i = t >> 1, j = t & 1;
        const float* s0 = sr4 + (2 * i) * 4 + 2 * j;
        sr2[t] = 0.25f * (s0[0] + s0[1] + s0[4] + s0[5]);
        r2_out[t] = sr2[t];
        float ws = -0.25f * sr2[t];
        wa[(2 * i) * 4 + 2 * j] = ws;
        wa[(2 * i) * 4 + 2 * j + 1] = ws;
        wa[(2 * i + 1) * 4 + 2 * j] = ws;
        wa[(2 * i + 1) * 4 + 2 * j + 1] = ws;
    }
    __syncthreads();

    auto step = [&](const float* win, const float* rl, float* wout, int s) {
        for (int idx = t; idx < s * s; idx += 1024) {
            int i = idx / s, j = idx - i * s;
            float up = i > 0 ? win[(i - 1) * s + j] : 0.f;
            float dn = i < s - 1 ? win[(i + 1) * s + j] : 0.f;
            float lf = j > 0 ? win[i * s + j - 1] : 0.f;
            float rt = j < s - 1 ? win[i * s + j + 1] : 0.f;
            float ws = 0.25f * (up + dn + lf + rt - rl[idx]);
            int o = 2 * s;
            wout[(2 * i) * o + 2 * j] = ws;
            wout[(2 * i) * o + 2 * j + 1] = ws;
            wout[(2 * i + 1) * o + 2 * j] = ws;
            wout[(2 * i + 1) * o + 2 * j + 1] = ws;
        }
    };
    step(wa, sr4, wb, 4);
    __syncthreads();
    step(wb, sr8, wa, 8);
    __syncthreads();
    step(wa, sr16, wb, 16);
    __syncthreads();
    step(wb, sr32, wa, 32);
    __syncthreads();
    step(wa, sr64, w128_out, 64);
}

// ======== mega MG step: prolong chain (w128->S1024) + p update (+halo) +
//          next residual + full restrict  (or LAST: out_p/out_w + u,v projection) ========
template <bool LAST>
__global__ __launch_bounds__(256) void k_mg_step(
    const float* __restrict__ p, const float* __restrict__ b,
    const float* __restrict__ w128,
    const float* __restrict__ r128, const float* __restrict__ r256,
    const float* __restrict__ r512, const float* __restrict__ r1024,
    float* __restrict__ pdst,
    float* __restrict__ o1024, float* __restrict__ o512,
    float* __restrict__ o256, float* __restrict__ o128,
    float* __restrict__ wout, float* __restrict__ un, float* __restrict__ vn)
{
    __shared__ float sw128[5][20];
    __shared__ float s128[3][18];
    __shared__ float s256[4][34];
    __shared__ float s512[6][66];
    __shared__ float s1024[10][132];
    __shared__ __align__(16) float pmid[20][264];
    __shared__ float pnew[18][258];
    __shared__ float red512[4][64];
    __shared__ float red256[2][32];

    const int jb = blockIdx.x * 256;
    const int ib = blockIdx.y * 16;
    const int tid = threadIdx.y * 64 + threadIdx.x;
    const int r1 = ib / 2 - 1,  c1 = jb / 2 - 1;    // s1024: 10x130
    const int r2 = ib / 4 - 1,  c2 = jb / 4 - 1;    // s512:  6x66
    const int r3 = ib / 8 - 1,  c3 = jb / 8 - 1;    // s256:  4x34
    const int r4 = ib / 16 - 1, c4 = jb / 16 - 1;   // s128:  3x18
    const int r5 = ib / 16 - 2, c5 = jb / 16 - 2;   // w128 tile: 5x20

    // stage w128 tile (zero-pad)
    if (tid < 100) {
        int r = tid / 20, c = tid - (tid / 20) * 20;
        int x = r5 + r, y = c5 + c;
        sw128[r][c] = ((unsigned)x < 128u && (unsigned)y < 128u) ? w128[x * 128 + y] : 0.f;
    }
    __syncthreads();
    // S128 = 0.25*(zsum(w128) - r128)
    if (tid < 54) {
        int r = tid / 18, c = tid - (tid / 18) * 18;
        int x = r4 + r, y = c4 + c;
        float v = 0.f;
        if ((unsigned)x < 128u && (unsigned)y < 128u) {
            float s = 0.f;
            if (x > 0)   s += sw128[r][c + 1];
            if (x < 127) s += sw128[r + 2][c + 1];
            if (y > 0)   s += sw128[r + 1][c];
            if (y < 127) s += sw128[r + 1][c + 2];
            v = 0.25f * (s - r128[x * 128 + y]);
        }
        s128[r][c] = v;
    }
    __syncthreads();
    // S256: w256(a,b) = S128[a>>1][b>>1]
    if (tid < 136) {
        int r = tid / 34, c = tid - (tid / 34) * 34;
        int x = r3 + r, y = c3 + c;
        float v = 0.f;
        if ((unsigned)x < 256u && (unsigned)y < 256u) {
            float s = 0.f;
            if (x > 0)   s += s128[((x - 1) >> 1) - r4][(y >> 1) - c4];
            if (x < 255) s += s128[((x + 1) >> 1) - r4][(y >> 1) - c4];
            if (y > 0)   s += s128[(x >> 1) - r4][((y - 1) >> 1) - c4];
            if (y < 255) s += s128[(x >> 1) - r4][((y + 1) >> 1) - c4];
            v = 0.25f * (s - r256[x * 256 + y]);
        }
        s256[r][c] = v;
    }
    __syncthreads();
    // S512
    for (int idx = tid; idx < 6 * 66; idx += 256) {
        int r = idx / 66, c = idx - (idx / 66) * 66;
        int x = r2 + r, y = c2 + c;
        float v = 0.f;
        if ((unsigned)x < 512u && (unsigned)y < 512u) {
            float s = 0.f;
            if (x > 0)   s += s256[((x - 1) >> 1) - r3][(y >> 1) - c3];
            if (x < 511) s += s256[((x + 1) >> 1) - r3][(y >> 1) - c3];
            if (y > 0)   s += s256[(x >> 1) - r3][((y - 1) >> 1) - c3];
            if (y < 511) s += s256[(x >> 1) - r3][((y + 1) >> 1) - c3];
            v = 0.25f * (s - r512[x * 512 + y]);
        }
        s512[r][c] = v;
    }
    __syncthreads();
    // S1024
    for (int idx = tid; idx < 10 * 130; idx += 256) {
        int r = idx / 130, c = idx - (idx / 130) * 130;
        int x = r1 + r, y = c1 + c;
        float v = 0.f;
        if ((unsigned)x < 1024u && (unsigned)y < 1024u) {
            float s = 0.f;
            if (x > 0)    s += s512[((x - 1) >> 1) - r2][(y >> 1) - c2];
            if (x < 1023) s += s512[((x + 1) >> 1) - r2][(y >> 1) - c2];
            if (y > 0)    s += s512[(x >> 1) - r2][((y - 1) >> 1) - c2];
            if (y < 1023) s += s512[(x >> 1) - r2][((y + 1) >> 1) - c2];
            v = 0.25f * (s - r1024[x * 1024 + y]);
        }
        s1024[r][c] = v;
    }
    __syncthreads();
    // p_mid = p - up(S1024) on rows ib-2..ib+17, stored cols jb-4..jb+259 (used jb-2..jb+257)
    for (int idx = tid; idx < 20 * 66; idx += 256) {
        int r = idx / 66, q = idx - (idx / 66) * 66;
        int gi = ib - 2 + r;
        int gj0 = jb - 4 + q * 4;
        float vals[4] = {0.f, 0.f, 0.f, 0.f};
        if ((unsigned)gi < (unsigned)NN) {
            if (gj0 >= 0 && gj0 + 3 < NN) {
                float4 pv = *reinterpret_cast<const float4*>(p + (size_t)gi * NN + gj0);
                vals[0] = pv.x; vals[1] = pv.y; vals[2] = pv.z; vals[3] = pv.w;
            } else {
#pragma unroll
                for (int q4 = 0; q4 < 4; ++q4) {
                    int gj = gj0 + q4;
                    vals[q4] = ((unsigned)gj < (unsigned)NN) ? p[(size_t)gi * NN + gj] : 0.f;
                }
            }
        }
#pragma unroll
        for (int q4 = 0; q4 < 4; ++q4) {
            int gj = gj0 + q4;
            float m = 0.f;
            if ((unsigned)gi < (unsigned)NN && (unsigned)gj < (unsigned)NN &&
                gj >= jb - 2 && gj <= jb + 257) {
                m = vals[q4] - s1024[(gi >> 1) - r1][(gj >> 1) - c1];
            }
            pmid[r][q * 4 + q4] = m;
        }
    }
    __syncthreads();
    // p_new = 0.25*(edge-sum(p_mid) - b) on rows ib-1..ib+16, cols jb-1..jb+256
    for (int idx = tid; idx < 18 * 258; idx += 256) {
        int r = idx / 258, c = idx - (idx / 258) * 258;
        int gi = ib - 1 + r, gj = jb - 1 + c;
        float v = 0.f;
        if ((unsigned)gi < (unsigned)NN && (unsigned)gj < (unsigned)NN) {
            int iu = gi > 0 ? gi - 1 : 0;
            int idn = gi < NN - 1 ? gi + 1 : NN - 1;
            int jl = gj > 0 ? gj - 1 : 0;
            int jr = gj < NN - 1 ? gj + 1 : NN - 1;
            float s = pmid[iu - (ib - 2)][gj - (jb - 4)] + pmid[idn - (ib - 2)][gj - (jb - 4)]
                    + pmid[gi - (ib - 2)][jl - (jb - 4)] + pmid[gi - (ib - 2)][jr - (jb - 4)];
            v = 0.25f * (s - b[(size_t)gi * NN + gj]);
        }
        pnew[r][c] = v;
    }
    __syncthreads();

    const int i0 = ib + threadIdx.y * 4;
    const int j0 = jb + threadIdx.x * 4;
    // write p_new center
#pragma unroll
    for (int rr = 0; rr < 4; ++rr) {
        int i = i0 + rr;
        int lr = i - (ib - 1);
        int lc = j0 - (jb - 1);
        *reinterpret_cast<float4*>(pdst + (size_t)i * NN + j0) =
            make_float4(pnew[lr][lc], pnew[lr][lc + 1], pnew[lr][lc + 2], pnew[lr][lc + 3]);
    }

    if (LAST) {
        const float DT = 0.01f;
#pragma unroll
        for (int rr = 0; rr < 4; ++rr) {
            int i = i0 + rr;
            int lr = i - (ib - 1);
            int s1r = (i >> 1) - r1;
            float ow[4];
#pragma unroll
            for (int c = 0; c < 4; ++c) ow[c] = s1024[s1r][((j0 + c) >> 1) - c1];
            store4(wout, i, j0, ow);
            float4 uu = *reinterpret_cast<float4*>(un + (size_t)i * NN + j0);
            float4 vv = *reinterpret_cast<float4*>(vn + (size_t)i * NN + j0);
            float ou[4] = {uu.x, uu.y, uu.z, uu.w};
            float ov[4] = {vv.x, vv.y, vv.z, vv.w};
            int iu = (i > 0 ? i - 1 : 0) - (ib - 1);
            int idn = (i < NN - 1 ? i + 1 : NN - 1) - (ib - 1);
#pragma unroll
            for (int c = 0; c < 4; ++c) {
                int j = j0 + c;
                int jl = (j > 0 ? j - 1 : 0) - (jb - 1);
                int jr = (j < NN - 1 ? j + 1 : NN - 1) - (jb - 1);
                int lc = j - (jb - 1);
                ou[c] -= 0.5f * (pnew[lr][jr] - pnew[lr][jl]) * DT;
                ov[c] -= 0.5f * (pnew[idn][lc] - pnew[iu][lc]) * DT;
            }
            store4(un, i, j0, ou);
            store4(vn, i, j0, ov);
        }
    } else {
        // residual of p_new (edge-pad) + restrict chain
        float res[4][4];
#pragma unroll
        for (int rr = 0; rr < 4; ++rr) {
#pragma unroll
            for (int cc = 0; cc < 4; ++cc) {
                int i = i0 + rr, j = j0 + cc;
                int lr = i - (ib - 1), lc = j - (jb - 1);
                int iu = (i > 0 ? i - 1 : 0) - (ib - 1);
                int idn = (i < NN - 1 ? i + 1 : NN - 1) - (ib - 1);
                int jl = (j > 0 ? j - 1 : 0) - (jb - 1);
                int jr = (j < NN - 1 ? j + 1 : NN - 1) - (jb - 1);
                res[rr][cc] = pnew[iu][lc] + pnew[idn][lc] + pnew[lr][jl] + pnew[lr][jr]
                            - 4.f * pnew[lr][lc] - b[(size_t)i * NN + j];
            }
        }
        int it = blockIdx.y * 4 + threadIdx.y;
        int jt = blockIdx.x * 64 + threadIdx.x;
        float q00 = 0.25f * (res[0][0] + res[0][1] + res[1][0] + res[1][1]);
        float q01 = 0.25f * (res[0][2] + res[0][3] + res[1][2] + res[1][3]);
        float q10 = 0.25f * (res[2][0] + res[2][1] + res[3][0] + res[3][1]);
        float q11 = 0.25f * (res[2][2] + res[2][3] + res[3][2] + res[3][3]);
        int ci = it * 2, cj = jt * 2;
        *reinterpret_cast<float2*>(o1024 + (size_t)ci * 1024 + cj)       = make_float2(q00, q01);
        *reinterpret_cast<float2*>(o1024 + (size_t)(ci + 1) * 1024 + cj) = make_float2(q10, q11);
        float s = 0.25f * (q00 + q01 + q10 + q11);
        o512[(size_t)it * 512 + jt] = s;
        red512[threadIdx.y][threadIdx.x] = s;
        __syncthreads();
        if (tid < 64) {
            int a = tid >> 5, c = tid & 31;
            float m = 0.25f * (red512[2 * a][2 * c] + red512[2 * a][2 * c + 1] +
                               red512[2 * a + 1][2 * c] + red512[2 * a + 1][2 * c + 1]);
            o256[(size_t)(blockIdx.y * 2 + a) * 256 + blockIdx.x * 32 + c] = m;
            red256[a][c] = m;
        }
        __syncthreads();
        if (tid < 16) {
            float m = 0.25f * (red256[0][2 * tid] + red256[0][2 * tid + 1] +
                               red256[1][2 * tid] + red256[1][2 * tid + 1]);
            o128[(size_t)blockIdx.y * 128 + blockIdx.x * 16 + tid] = m;
        }
    }
}

extern "C" void kernel_launch(void* const* d_in, const int* in_sizes, int n_in,
                              void* d_out, int out_size, void* d_ws, size_t ws_size,
                              hipStream_t stream) {
    const float* u  = (const float*)d_in[0];
    const float* v  = (const float*)d_in[1];
    const float* p  = (const float*)d_in[2];
    const float* Fx = (const float*)d_in[3];
    const float* Fy = (const float*)d_in[4];
    const float* k1 = (const float*)d_in[5];

    float* out = (float*)d_out;
    float* out_u = out;
    float* out_v = out + (size_t)NN2;
    float* out_p = out + 2 * (size_t)NN2;
    float* out_w = out + 3 * (size_t)NN2;
    float* out_r = out + 4 * (size_t)NN2;

    float* ws = (float*)d_ws;
    float* b  = ws;
    float* pA = ws + (size_t)NN2;
    float* pB = ws + 2 * (size_t)NN2;
    float* base = ws + 3 * (size_t)NN2;
    // r pyramid A
    float* rA1024 = base;
    float* rA512  = rA1024 + 1024 * 1024;
    float* rA256  = rA512 + 512 * 512;
    float* rA128  = rA256 + 256 * 256;
    // r pyramid B
    float* rB1024 = rA128 + 128 * 128;
    float* rB512  = rB1024 + 1024 * 1024;
    float* rB256  = rB512 + 512 * 512;
    float* rB128  = rB256 + 256 * 256;
    float* w128   = rB128 + 128 * 128;

    // b_u/b_v live in not-yet-needed output regions
    float* bu = out_w;
    float* bv = out_p;

    dim3 blk(64, 4);
    dim3 blkT(16, 16);
    dim3 gT(32, 64);
    dim3 gM(8, 128);

    // momentum
    k_pred_f<<<gT, blkT, 0, stream>>>(u, v, k1, p, bu, bv);
    k_corr_f<<<gT, blkT, 0, stream>>>(u, v, k1, p, bu, bv, Fx, Fy, out_u, out_v);
    // b + initial residual pyramid (A)
    k_rhs_res<<<gM, blk, 0, stream>>>(out_u, out_v, p, b, rA1024, rA512, rA256, rA128);

    const float* pcur = p;
    for (int it = 0; it < 5; ++it) {
        const bool useA = (it % 2 == 0);
        const float* R1024 = useA ? rA1024 : rB1024;
        const float* R512  = useA ? rA512  : rB512;
        const float* R256  = useA ? rA256  : rB256;
        const float* R128  = useA ? rA128  : rB128;
        float* O1024 = useA ? rB1024 : rA1024;
        float* O512  = useA ? rB512  : rA512;
        float* O256  = useA ? rB256  : rA256;
        float* O128  = useA ? rB128  : rA128;

        k_small<<<1, 1024, 0, stream>>>(R128, w128, out_r);
        if (it < 4) {
            float* pdst = (it & 1) ? pB : pA;
            k_mg_step<false><<<gM, blk, 0, stream>>>(pcur, b, w128, R128, R256, R512, R1024,
                                                     pdst, O1024, O512, O256, O128,
                                                     nullptr, nullptr, nullptr);
            pcur = pdst;
        } else {
            k_mg_step<true><<<gM, blk, 0, stream>>>(pcur, b, w128, R128, R256, R512, R1024,
                                                    out_p, nullptr, nullptr, nullptr, nullptr,
                                                    out_w, out_u, out_v);
        }
    }
}

// Round 5
// 393.150 us; speedup vs baseline: 1.1677x; 1.1677x over previous
//
#include <hip/hip_runtime.h>

#define NN 2048
#define NN2 (NN * NN)

// ---- vector load helpers ----
__device__ __forceinline__ void load6z(const float* __restrict__ A, int i, int j0, float a[6]) {
    if ((unsigned)i >= (unsigned)NN) {
#pragma unroll
        for (int q = 0; q < 6; ++q) a[q] = 0.f;
        return;
    }
    const float* row = A + (size_t)i * NN;
    float4 c = *reinterpret_cast<const float4*>(row + j0);
    a[1] = c.x; a[2] = c.y; a[3] = c.z; a[4] = c.w;
    a[0] = (j0 > 0) ? row[j0 - 1] : 0.f;
    a[5] = (j0 + 4 < NN) ? row[j0 + 4] : 0.f;
}
__device__ __forceinline__ void load4z(const float* __restrict__ A, int i, int j0, float a[4]) {
    if ((unsigned)i >= (unsigned)NN) {
#pragma unroll
        for (int q = 0; q < 4; ++q) a[q] = 0.f;
        return;
    }
    float4 c = *reinterpret_cast<const float4*>(A + (size_t)i * NN + j0);
    a[0] = c.x; a[1] = c.y; a[2] = c.z; a[3] = c.w;
}
__device__ __forceinline__ void load6e(const float* __restrict__ A, int i, int j0, float a[6]) {
    i = i < 0 ? 0 : (i > NN - 1 ? NN - 1 : i);
    const float* row = A + (size_t)i * NN;
    float4 c = *reinterpret_cast<const float4*>(row + j0);
    a[1] = c.x; a[2] = c.y; a[3] = c.z; a[4] = c.w;
    a[0] = (j0 > 0) ? row[j0 - 1] : c.x;
    a[5] = (j0 + 4 < NN) ? row[j0 + 4] : c.w;
}
__device__ __forceinline__ void load4e(const float* __restrict__ A, int i, int j0, float a[4]) {
    i = i < 0 ? 0 : (i > NN - 1 ? NN - 1 : i);
    float4 c = *reinterpret_cast<const float4*>(A + (size_t)i * NN + j0);
    a[0] = c.x; a[1] = c.y; a[2] = c.z; a[3] = c.w;
}
__device__ __forceinline__ void store4(float* __restrict__ A, int i, int j0, const float a[4]) {
    *reinterpret_cast<float4*>(A + (size_t)i * NN + j0) = make_float4(a[0], a[1], a[2], a[3]);
}

// ===================== fused pg1 + predictor (16-row tile) =====================
__global__ __launch_bounds__(256) void k_pred_f(const float* __restrict__ u, const float* __restrict__ v,
                                                const float* __restrict__ k1, const float* __restrict__ p,
                                                float* __restrict__ bu, float* __restrict__ bv) {
    const float DT = 0.01f;
    __shared__ __align__(16) float su[20][72], sv[20][72];
    __shared__ float sku[18][68], skv[18][68];
    const int jb = blockIdx.x * 64;
    const int ib = blockIdx.y * 16;
    const int tid = threadIdx.y * 16 + threadIdx.x;

    // stage u,v rows ib-2..ib+17, cols jb-4..jb+67 (zero-pad)
    for (int idx = tid; idx < 20 * 18; idx += 256) {
        int r = idx / 18, c4 = idx - r * 18;
        int gi = ib - 2 + r;
        int gj = jb - 4 + c4 * 4;
        float4 uu = make_float4(0.f, 0.f, 0.f, 0.f), vv = uu;
        if ((unsigned)gi < (unsigned)NN) {
            if (gj >= 0 && gj + 3 < NN) {
                uu = *reinterpret_cast<const float4*>(u + (size_t)gi * NN + gj);
                vv = *reinterpret_cast<const float4*>(v + (size_t)gi * NN + gj);
            } else {
                float tu[4], tv[4];
#pragma unroll
                for (int q = 0; q < 4; ++q) {
                    int g = gj + q;
                    bool in = (unsigned)g < (unsigned)NN;
                    tu[q] = in ? u[(size_t)gi * NN + g] : 0.f;
                    tv[q] = in ? v[(size_t)gi * NN + g] : 0.f;
                }
                uu = make_float4(tu[0], tu[1], tu[2], tu[3]);
                vv = make_float4(tv[0], tv[1], tv[2], tv[3]);
            }
        }
        *reinterpret_cast<float4*>(&su[r][c4 * 4]) = uu;
        *reinterpret_cast<float4*>(&sv[r][c4 * 4]) = vv;
    }
    __syncthreads();

    // k on rows ib-1..ib+16 (18), cols jb-1..jb+64 (66)
    for (int idx = tid; idx < 18 * 66; idx += 256) {
        int r = idx / 66, c = idx - r * 66;
        int gi = ib - 1 + r, gj = jb - 1 + c;
        float kuo = 0.f, kvo = 0.f;
        if ((unsigned)gi < (unsigned)NN && (unsigned)gj < (unsigned)NN) {
            int lr = r + 1, lc = c + 3;
            float uc = su[lr][lc], ul = su[lr][lc - 1], ur = su[lr][lc + 1], ut = su[lr - 1][lc], ub = su[lr + 1][lc];
            float vc = sv[lr][lc], vl = sv[lr][lc - 1], vr = sv[lr][lc + 1], vt = sv[lr - 1][lc], vb = sv[lr + 1][lc];
            float ADxu = 0.5f * (ur - ul), ADyu = 0.5f * (ub - ut);
            float ADxv = 0.5f * (vr - vl), ADyv = 0.5f * (vb - vt);
            float Lu = ul + ur + ut + ub - 4.f * uc;
            float Lv = vl + vr + vt + vb - 4.f * vc;
            float s = fabsf(uc) + fabsf(vc);
            float kuv = 0.25f * fabsf(0.5f * s * Lu) / (0.001f + 0.5f * (fabsf(ADxu) + fabsf(ADyu)));
            float kvv = 0.25f * fabsf(0.5f * s * Lv) / (0.001f + 0.5f * (fabsf(ADxv) + fabsf(ADyv)));
            float k1c = k1[(size_t)gi * NN + gj];
            kuo = fminf(kuv, k1c);
            kvo = fminf(kvv, k1c);
        }
        sku[r][c] = kuo;
        skv[r][c] = kvo;
    }
    __syncthreads();

    const int i = ib + threadIdx.y;
    const int j0 = jb + threadIdx.x * 4;
    float p6[6], pu[4], pd[4], obu[4], obv[4];
    load6e(p, i, j0, p6); load4e(p, i - 1, j0, pu); load4e(p, i + 1, j0, pd);
    const int lur = threadIdx.y + 2, lkr = threadIdx.y + 1;
#pragma unroll
    for (int c = 0; c < 4; ++c) {
        int luc = threadIdx.x * 4 + c + 4, lkc = threadIdx.x * 4 + c + 1;
        float uc = su[lur][luc], ul = su[lur][luc - 1], ur = su[lur][luc + 1], ut = su[lur - 1][luc], ub = su[lur + 1][luc];
        float vc = sv[lur][luc], vl = sv[lur][luc - 1], vr = sv[lur][luc + 1], vt = sv[lur - 1][luc], vb = sv[lur + 1][luc];
        float kuc = sku[lkr][lkc], kul = sku[lkr][lkc - 1], kur = sku[lkr][lkc + 1], kut = sku[lkr - 1][lkc], kub = sku[lkr + 1][lkc];
        float kvc = skv[lkr][lkc], kvl = skv[lkr][lkc - 1], kvr = skv[lkr][lkc + 1], kvt = skv[lkr - 1][lkc], kvb = skv[lkr + 1][lkc];
        float ADxu = 0.5f * (ur - ul), ADyu = 0.5f * (ub - ut);
        float ADxv = 0.5f * (vr - vl), ADyv = 0.5f * (vb - vt);
        float Lu = ul + ur + ut + ub - 4.f * uc;
        float Lv = vl + vr + vt + vb - 4.f * vc;
        float Lku = kul + kur + kut + kub - 4.f * kuc;
        float Lkv = kvl + kvr + kvt + kvb - 4.f * kvc;
        float Luku = ul * kul + ur * kur + ut * kut + ub * kub - 4.f * uc * kuc;
        float Lvkv = vl * kvl + vr * kvr + vt * kvt + vb * kvb - 4.f * vc * kvc;
        float kx = 1.5f * (kuc * Lu + Luku - uc * Lku);
        float ky = 1.5f * (kvc * Lv + Lvkv - vc * Lkv);
        float Grapx = 0.5f * (p6[c + 2] - p6[c]) * DT;
        float Grapy = 0.5f * (pd[c] - pu[c]) * DT;
        obu[c] = uc + 0.5f * (kx * DT - uc * ADxu * DT - vc * ADyu * DT) - Grapx;
        obv[c] = vc + 0.5f * (ky * DT - uc * ADxv * DT - vc * ADyv * DT) - Grapy;
    }
    store4(bu, i, j0, obu);
    store4(bv, i, j0, obv);
}

// ===================== fused pg1(b) + corrector (16-row tile) =====================
__global__ __launch_bounds__(256) void k_corr_f(const float* __restrict__ u, const float* __restrict__ v,
                                                const float* __restrict__ k1, const float* __restrict__ p,
                                                const float* __restrict__ bu, const float* __restrict__ bv,
                                                const float* __restrict__ Fx, const float* __restrict__ Fy,
                                                float* __restrict__ un, float* __restrict__ vn) {
    const float DT = 0.01f;
    __shared__ __align__(16) float sbu[20][72], sbv[20][72];
    __shared__ float sku[18][68], skv[18][68];
    const int jb = blockIdx.x * 64;
    const int ib = blockIdx.y * 16;
    const int tid = threadIdx.y * 16 + threadIdx.x;

    for (int idx = tid; idx < 20 * 18; idx += 256) {
        int r = idx / 18, c4 = idx - r * 18;
        int gi = ib - 2 + r;
        int gj = jb - 4 + c4 * 4;
        float4 uu = make_float4(0.f, 0.f, 0.f, 0.f), vv = uu;
        if ((unsigned)gi < (unsigned)NN) {
            if (gj >= 0 && gj + 3 < NN) {
                uu = *reinterpret_cast<const float4*>(bu + (size_t)gi * NN + gj);
                vv = *reinterpret_cast<const float4*>(bv + (size_t)gi * NN + gj);
            } else {
                float tu[4], tv[4];
#pragma unroll
                for (int q = 0; q < 4; ++q) {
                    int g = gj + q;
                    bool in = (unsigned)g < (unsigned)NN;
                    tu[q] = in ? bu[(size_t)gi * NN + g] : 0.f;
                    tv[q] = in ? bv[(size_t)gi * NN + g] : 0.f;
                }
                uu = make_float4(tu[0], tu[1], tu[2], tu[3]);
                vv = make_float4(tv[0], tv[1], tv[2], tv[3]);
            }
        }
        *reinterpret_cast<float4*>(&sbu[r][c4 * 4]) = uu;
        *reinterpret_cast<float4*>(&sbv[r][c4 * 4]) = vv;
    }
    __syncthreads();

    for (int idx = tid; idx < 18 * 66; idx += 256) {
        int r = idx / 66, c = idx - r * 66;
        int gi = ib - 1 + r, gj = jb - 1 + c;
        float kuo = 0.f, kvo = 0.f;
        if ((unsigned)gi < (unsigned)NN && (unsigned)gj < (unsigned)NN) {
            int lr = r + 1, lc = c + 3;
            float uc = sbu[lr][lc], ul = sbu[lr][lc - 1], ur = sbu[lr][lc + 1], ut = sbu[lr - 1][lc], ub = sbu[lr + 1][lc];
            float vc = sbv[lr][lc], vl = sbv[lr][lc - 1], vr = sbv[lr][lc + 1], vt = sbv[lr - 1][lc], vb = sbv[lr + 1][lc];
            float ADxu = 0.5f * (ur - ul), ADyu = 0.5f * (ub - ut);
            float ADxv = 0.5f * (vr - vl), ADyv = 0.5f * (vb - vt);
            float Lu = ul + ur + ut + ub - 4.f * uc;
            float Lv = vl + vr + vt + vb - 4.f * vc;
            float s = fabsf(uc) + fabsf(vc);
            float kuv = 0.25f * fabsf(0.5f * s * Lu) / (0.001f + 0.5f * (fabsf(ADxu) + fabsf(ADyu)));
            float kvv = 0.25f * fabsf(0.5f * s * Lv) / (0.001f + 0.5f * (fabsf(ADxv) + fabsf(ADyv)));
            float k1c = k1[(size_t)gi * NN + gj];
            kuo = fminf(kuv, k1c);
            kvo = fminf(kvv, k1c);
        }
        sku[r][c] = kuo;
        skv[r][c] = kvo;
    }
    __syncthreads();

    const int i = ib + threadIdx.y;
    const int j0 = jb + threadIdx.x * 4;
    float p6[6], pu[4], pd[4];
    float u6[6], uu[4], ud[4], v6[6], vu[4], vd[4], fx[4], fy[4], oun[4], ovn[4];
    load6e(p, i, j0, p6); load4e(p, i - 1, j0, pu); load4e(p, i + 1, j0, pd);
    load6z(u, i, j0, u6); load4z(u, i - 1, j0, uu); load4z(u, i + 1, j0, ud);
    load6z(v, i, j0, v6); load4z(v, i - 1, j0, vu); load4z(v, i + 1, j0, vd);
    load4z(Fx, i, j0, fx); load4z(Fy, i, j0, fy);
    const int lbr = threadIdx.y + 2, lkr = threadIdx.y + 1;
#pragma unroll
    for (int c = 0; c < 4; ++c) {
        int lbc = threadIdx.x * 4 + c + 4, lkc = threadIdx.x * 4 + c + 1;
        float buc = sbu[lbr][lbc], bul = sbu[lbr][lbc - 1], bur = sbu[lbr][lbc + 1], but = sbu[lbr - 1][lbc], bub = sbu[lbr + 1][lbc];
        float bvc = sbv[lbr][lbc], bvl = sbv[lbr][lbc - 1], bvr = sbv[lbr][lbc + 1], bvt = sbv[lbr - 1][lbc], bvb = sbv[lbr + 1][lbc];
        float kuc = sku[lkr][lkc], kul = sku[lkr][lkc - 1], kur = sku[lkr][lkc + 1], kut = sku[lkr - 1][lkc], kub = sku[lkr + 1][lkc];
        float kvc = skv[lkr][lkc], kvl = skv[lkr][lkc - 1], kvr = skv[lkr][lkc + 1], kvt = skv[lkr - 1][lkc], kvb = skv[lkr + 1][lkc];
        float uc = u6[c + 1], ul = u6[c], ur = u6[c + 2], ut = uu[c], ub = ud[c];
        float vc = v6[c + 1], vl = v6[c], vr = v6[c + 2], vt = vu[c], vb = vd[c];
        float ADxbu = 0.5f * (bur - bul), ADybu = 0.5f * (bub - but);
        float ADxbv = 0.5f * (bvr - bvl), ADybv = 0.5f * (bvb - bvt);
        float Lbu = bul + bur + but + bub - 4.f * buc;
        float Lbv = bvl + bvr + bvt + bvb - 4.f * bvc;
        float Lku = kul + kur + kut + kub - 4.f * kuc;
        float Lkv = kvl + kvr + kvt + kvb - 4.f * kvc;
        // product term uses ORIGINAL velocities
        float Luku = ul * kul + ur * kur + ut * kut + ub * kub - 4.f * uc * kuc;
        float Lvkv = vl * kvl + vr * kvr + vt * kvt + vb * kvb - 4.f * vc * kvc;
        float kx = 1.5f * (kuc * Lbu + Luku - buc * Lku);
        float ky = 1.5f * (kvc * Lbv + Lvkv - bvc * Lkv);
        float Grapx = 0.5f * (p6[c + 2] - p6[c]) * DT;
        float Grapy = 0.5f * (pd[c] - pu[c]) * DT;
        oun[c] = uc + kx * DT - buc * ADxbu * DT - bvc * ADybu * DT - Grapx - fx[c] * DT;
        ovn[c] = vc + ky * DT - buc * ADxbv * DT - bvc * ADybv * DT - Grapy - fy[c] * DT;
    }
    store4(un, i, j0, oun);
    store4(vn, i, j0, ovn);
}

// -------- fused: b = -div(un,vn)/DT + residual(p,b) + restrict to 1024/512/256 --------
__global__ __launch_bounds__(256) void k_rhs_res(const float* __restrict__ un, const float* __restrict__ vn,
                                                 const float* __restrict__ p, float* __restrict__ b,
                                                 float* __restrict__ r1024, float* __restrict__ r512,
                                                 float* __restrict__ r256) {
    __shared__ float s512r[4][64];
    int tx = threadIdx.x, ty = threadIdx.y;
    int jt = blockIdx.x * 64 + tx;
    int it = blockIdx.y * 4 + ty;
    int j0 = jt * 4, i0 = it * 4;
    float bb[4][4];
#pragma unroll
    for (int r = 0; r < 4; ++r) {
        float u6[6], vu[4], vd[4];
        load6z(un, i0 + r, j0, u6);
        load4z(vn, i0 + r - 1, j0, vu);
        load4z(vn, i0 + r + 1, j0, vd);
#pragma unroll
        for (int c = 0; c < 4; ++c)
            bb[r][c] = -100.f * (0.5f * (u6[c + 2] - u6[c]) + 0.5f * (vd[c] - vu[c]));
        store4(b, i0 + r, j0, bb[r]);
    }
    float p6[6][6];
#pragma unroll
    for (int r = 0; r < 6; ++r) load6e(p, i0 - 1 + r, j0, p6[r]);
    float res[4][4];
#pragma unroll
    for (int r = 0; r < 4; ++r)
#pragma unroll
        for (int c = 0; c < 4; ++c) {
            float pc = p6[r + 1][c + 1];
            res[r][c] = p6[r][c + 1] + p6[r + 2][c + 1] + p6[r + 1][c] + p6[r + 1][c + 2] - 4.f * pc - bb[r][c];
        }
    float q00 = 0.25f * (res[0][0] + res[0][1] + res[1][0] + res[1][1]);
    float q01 = 0.25f * (res[0][2] + res[0][3] + res[1][2] + res[1][3]);
    float q10 = 0.25f * (res[2][0] + res[2][1] + res[3][0] + res[3][1]);
    float q11 = 0.25f * (res[2][2] + res[2][3] + res[3][2] + res[3][3]);
    int ci = it * 2, cj = jt * 2;
    *reinterpret_cast<float2*>(r1024 + (size_t)ci * 1024 + cj)       = make_float2(q00, q01);
    *reinterpret_cast<float2*>(r1024 + (size_t)(ci + 1) * 1024 + cj) = make_float2(q10, q11);
    float s = 0.25f * (q00 + q01 + q10 + q11);
    r512[(size_t)it * 512 + jt] = s;
    s512r[ty][tx] = s;
    __syncthreads();
    int tid = ty * 64 + tx;
    if (tid < 64) {
        int a = tid >> 5, c = tid & 31;
        float m = 0.25f * (s512r[2 * a][2 * c] + s512r[2 * a][2 * c + 1] + s512r[2 * a + 1][2 * c] + s512r[2 * a + 1][2 * c + 1]);
        r256[(size_t)(blockIdx.y * 2 + a) * 256 + blockIdx.x * 32 + c] = m;
    }
}

// ---------------- coarse levels: r256 -> (r128 out) -> ... -> w128, r2 ----------------
__global__ __launch_bounds__(1024) void k_small2(const float* __restrict__ r256in,
                                                 float* __restrict__ r128g,
                                                 float* __restrict__ w128_out,
                                                 float* __restrict__ r2_out) {
    __shared__ float sr128[128 * 128];
    __shared__ float sr64[64 * 64];
    __shared__ float sr32[32 * 32];
    __shared__ float sr16[16 * 16];
    __shared__ float sr8[8 * 8];
    __shared__ float sr4[16];
    __shared__ float sr2[4];
    __shared__ float wa[64 * 64];
    __shared__ float wb[64 * 64];
    int t = threadIdx.x;

    for (int idx = t; idx < 128 * 128; idx += 1024) {
        int i = idx >> 7, j = idx & 127;
        const float* s0 = r256in + (2 * i) * 256 + 2 * j;
        float m = 0.25f * (s0[0] + s0[1] + s0[256] + s0[257]);
        sr128[idx] = m;
        r128g[idx] = m;
    }
    __syncthreads();
    for (int idx = t; idx < 64 * 64; idx += 1024) {
        int i = idx >> 6, j = idx & 63;
        const float* s0 = sr128 + (2 * i) * 128 + 2 * j;
        sr64[idx] = 0.25f * (s0[0] + s0[1] + s0[128] + s0[129]);
    }
    __syncthreads();
    if (t < 32 * 32) {
        int i = t >> 5, j = t & 31;
        const float* s0 = sr64 + (2 * i) * 64 + 2 * j;
        sr32[t] = 0.25f * (s0[0] + s0[1] + s0[64] + s0[65]);
    }
    __syncthreads();
    if (t < 16 * 16) {
        int i = t >> 4, j = t & 15;
        const float* s0 = sr32 + (2 * i) * 32 + 2 * j;
        sr16[t] = 0.25f * (s0[0] + s0[1] + s0[32] + s0[33]);
    }
    __syncthreads();
    if (t < 64) {
        int i = t >> 3, j = t & 7;
        const float* s0 = sr16 + (2 * i) * 16 + 2 * j;
        sr8[t] = 0.25f * (s0[0] + s0[1] + s0[16] + s0[17]);
    }
    __syncthreads();
    if (t < 16) {
        int i = t >> 2, j = t & 3;
        const float* s0 = sr8 + (2 * i) * 8 + 2 * j;
        sr4[t] = 0.25f * (s0[0] + s0[1] + s0[8] + s0[9]);
    }
    __syncthreads();
    if (t < 4) {
        int i = t >> 1, j = t & 1;
        const float* s0 = sr4 + (2 * i) * 4 + 2 * j;
        sr2[t] = 0.25f * (s0[0] + s0[1] + s0[4] + s0[5]);
        r2_out[t] = sr2[t];
        float ws = -0.25f * sr2[t];
        wa[(2 * i) * 4 + 2 * j] = ws;
        wa[(2 * i) * 4 + 2 * j + 1] = ws;
        wa[(2 * i + 1) * 4 + 2 * j] = ws;
        wa[(2 * i + 1) * 4 + 2 * j + 1] = ws;
    }
    __syncthreads();

    auto step = [&](const float* win, const float* rl, float* wout, int s) {
        for (int idx = t; idx < s * s; idx += 1024) {
            int i = idx / s, j = idx - i * s;
            float up = i > 0 ? win[(i - 1) * s + j] : 0.f;
            float dn = i < s - 1 ? win[(i + 1) * s + j] : 0.f;
            float lf = j > 0 ? win[i * s + j - 1] : 0.f;
            float rt = j < s - 1 ? win[i * s + j + 1] : 0.f;
            float ws = 0.25f * (up + dn + lf + rt - rl[idx]);
            int o = 2 * s;
            wout[(2 * i) * o + 2 * j] = ws;
            wout[(2 * i) * o + 2 * j + 1] = ws;
            wout[(2 * i + 1) * o + 2 * j] = ws;
            wout[(2 * i + 1) * o + 2 * j + 1] = ws;
        }
    };
    step(wa, sr4, wb, 4);
    __syncthreads();
    step(wb, sr8, wa, 8);
    __syncthreads();
    step(wa, sr16, wb, 16);
    __syncthreads();
    step(wb, sr32, wa, 32);
    __syncthreads();
    step(wa, sr64, w128_out, 64);
}

// ---------------- fused prolong: (w128, r128) -> S128s -> (r256) -> w512 ----------------
__global__ __launch_bounds__(256) void k_prolong2(const float* __restrict__ w128, const float* __restrict__ r128,
                                                  const float* __restrict__ r256, float* __restrict__ w512) {
    __shared__ float sw[5][68];
    __shared__ float s128[3][66];
    __shared__ float s256[2][128];
    const int jb = blockIdx.x * 256;        // w512 cols
    const int ob = blockIdx.y * 4;          // w512 rows
    const int by = blockIdx.y;
    const int rw = by - 2, cw = jb / 4 - 2; // w128 tile base (5x68)
    const int rs = by - 1, cs = jb / 4 - 1; // S128s base (3x66)
    const int tid = threadIdx.y * 64 + threadIdx.x;

    for (int idx = tid; idx < 5 * 68; idx += 256) {
        int r = idx / 68, c = idx - r * 68;
        int x = rw + r, y = cw + c;
        sw[r][c] = ((unsigned)x < 128u && (unsigned)y < 128u) ? w128[x * 128 + y] : 0.f;
    }
    __syncthreads();
    if (tid < 3 * 66) {
        int r = tid / 66, c = tid - (tid / 66) * 66;
        int x = rs + r, y = cs + c;
        float val = 0.f;
        if ((unsigned)x < 128u && (unsigned)y < 128u) {
            int lr = r + 1, lc = c + 1;
            val = 0.25f * (sw[lr - 1][lc] + sw[lr + 1][lc] + sw[lr][lc - 1] + sw[lr][lc + 1] - r128[x * 128 + y]);
        }
        s128[r][c] = val;
    }
    __syncthreads();
    {
        int rr = tid >> 7, cc = tid & 127;   // 2 x 128
        int X = 2 * by + rr, Y = jb / 2 + cc;
        float s = 0.f;
        if (X > 0)   s += s128[((X - 1) >> 1) - rs][(Y >> 1) - cs];
        if (X < 255) s += s128[((X + 1) >> 1) - rs][(Y >> 1) - cs];
        if (Y > 0)   s += s128[(X >> 1) - rs][((Y - 1) >> 1) - cs];
        if (Y < 255) s += s128[(X >> 1) - rs][((Y + 1) >> 1) - cs];
        s256[rr][cc] = 0.25f * (s - r256[X * 256 + Y]);
    }
    __syncthreads();
    const int i = ob + threadIdx.y;
    const int j0 = jb + threadIdx.x * 4;
    const int lr = (i >> 1) - 2 * by;
    float o[4];
#pragma unroll
    for (int c = 0; c < 4; ++c) o[c] = s256[lr][((j0 + c) >> 1) - jb / 2];
    *reinterpret_cast<float4*>(w512 + (size_t)i * 512 + j0) = make_float4(o[0], o[1], o[2], o[3]);
}

// ======== fused p-update: (w512,r512,r1024) -> S1024s -> p_new (+halo in LDS)
//          + next residual + restrict 1024/512/256  (LAST: out_p/out_w + projection) ========
template <bool LAST>
__global__ __launch_bounds__(256) void k_pupd3(
    const float* __restrict__ p, const float* __restrict__ b,
    const float* __restrict__ w512, const float* __restrict__ r512,
    const float* __restrict__ r1024,
    float* __restrict__ pdst,
    float* __restrict__ o1024, float* __restrict__ o512, float* __restrict__ o256,
    float* __restrict__ wout, float* __restrict__ un, float* __restrict__ vn)
{
    __shared__ float sW[6][38];
    __shared__ float sS[4][36];
    __shared__ float ws[6][68];
    __shared__ __align__(16) float pmid[12][136];
    __shared__ float pnew[10][130];
    __shared__ float sq[4][64];
    __shared__ float red[2][32];

    const int jb = blockIdx.x * 128;
    const int ib = blockIdx.y * 8;
    const int tid = threadIdx.y * 32 + threadIdx.x;
    const int r1 = ib / 2 - 1, c1 = jb / 2 - 2;   // ws 6x68 (S1024s)
    const int r2 = ib / 4 - 1, c2 = jb / 4 - 2;   // sS 4x36 (S512s)
    const int r3 = ib / 4 - 2, c3 = jb / 4 - 3;   // sW 6x38 (w512)

    for (int idx = tid; idx < 6 * 38; idx += 256) {
        int r = idx / 38, c = idx - r * 38;
        int x = r3 + r, y = c3 + c;
        sW[r][c] = ((unsigned)x < 512u && (unsigned)y < 512u) ? w512[(size_t)x * 512 + y] : 0.f;
    }
    __syncthreads();
    if (tid < 4 * 36) {
        int r = tid / 36, c = tid - (tid / 36) * 36;
        int x = r2 + r, y = c2 + c;
        float val = 0.f;
        if ((unsigned)x < 512u && (unsigned)y < 512u) {
            int lr = r + 1, lc = c + 1;
            val = 0.25f * (sW[lr - 1][lc] + sW[lr + 1][lc] + sW[lr][lc - 1] + sW[lr][lc + 1]
                           - r512[(size_t)x * 512 + y]);
        }
        sS[r][c] = val;
    }
    __syncthreads();
    for (int idx = tid; idx < 6 * 68; idx += 256) {
        int r = idx / 68, c = idx - r * 68;
        int x = r1 + r, y = c1 + c;
        float val = 0.f;
        if ((unsigned)x < 1024u && (unsigned)y < 1024u) {
            float s = 0.f;
            if (x > 0)    s += sS[((x - 1) >> 1) - r2][(y >> 1) - c2];
            if (x < 1023) s += sS[((x + 1) >> 1) - r2][(y >> 1) - c2];
            if (y > 0)    s += sS[(x >> 1) - r2][((y - 1) >> 1) - c2];
            if (y < 1023) s += sS[(x >> 1) - r2][((y + 1) >> 1) - c2];
            val = 0.25f * (s - r1024[(size_t)x * 1024 + y]);
        }
        ws[r][c] = val;
    }
    __syncthreads();
    // pmid = p - up(S1024s): rows ib-2..ib+9, cols jb-4..jb+131 (valid jb-2..jb+129)
    for (int idx = tid; idx < 12 * 34; idx += 256) {
        int r = idx / 34, q = idx - r * 34;
        int gi = ib - 2 + r;
        int gj0 = jb - 4 + q * 4;
        float vals[4] = {0.f, 0.f, 0.f, 0.f};
        if ((unsigned)gi < (unsigned)NN) {
            if (gj0 >= 0 && gj0 + 3 < NN) {
                float4 pv = *reinterpret_cast<const float4*>(p + (size_t)gi * NN + gj0);
                vals[0] = pv.x; vals[1] = pv.y; vals[2] = pv.z; vals[3] = pv.w;
            } else {
#pragma unroll
                for (int q4 = 0; q4 < 4; ++q4) {
                    int gj = gj0 + q4;
                    vals[q4] = ((unsigned)gj < (unsigned)NN) ? p[(size_t)gi * NN + gj] : 0.f;
                }
            }
        }
#pragma unroll
        for (int q4 = 0; q4 < 4; ++q4) {
            int gj = gj0 + q4;
            float m = 0.f;
            if ((unsigned)gi < (unsigned)NN && (unsigned)gj < (unsigned)NN &&
                gj >= jb - 2 && gj <= jb + 129) {
                m = vals[q4] - ws[(gi >> 1) - r1][(gj >> 1) - c1];
            }
            pmid[r][q * 4 + q4] = m;
        }
    }
    __syncthreads();
    // p_new = 0.25*(edge-sum(pmid) - b): rows ib-1..ib+8, cols jb-1..jb+128
    for (int idx = tid; idx < 10 * 130; idx += 256) {
        int r = idx / 130, c = idx - r * 130;
        int gi = ib - 1 + r, gj = jb - 1 + c;
        float val = 0.f;
        if ((unsigned)gi < (unsigned)NN && (unsigned)gj < (unsigned)NN) {
            int iu = gi > 0 ? gi - 1 : 0;
            int idn = gi < NN - 1 ? gi + 1 : NN - 1;
            int jl = gj > 0 ? gj - 1 : 0;
            int jr = gj < NN - 1 ? gj + 1 : NN - 1;
            float s = pmid[iu - (ib - 2)][gj - (jb - 4)] + pmid[idn - (ib - 2)][gj - (jb - 4)]
                    + pmid[gi - (ib - 2)][jl - (jb - 4)] + pmid[gi - (ib - 2)][jr - (jb - 4)];
            val = 0.25f * (s - b[(size_t)gi * NN + gj]);
        }
        pnew[r][c] = val;
    }
    __syncthreads();

    const int i  = ib + threadIdx.y;      // 8 rows
    const int j0 = jb + threadIdx.x * 4;  // 128 cols
    const int lr = i - (ib - 1);
    const int lc = j0 - (jb - 1);
    *reinterpret_cast<float4*>(pdst + (size_t)i * NN + j0) =
        make_float4(pnew[lr][lc], pnew[lr][lc + 1], pnew[lr][lc + 2], pnew[lr][lc + 3]);

    if (LAST) {
        const float DT = 0.01f;
        float ow[4];
        int wr = (i >> 1) - r1;
#pragma unroll
        for (int c = 0; c < 4; ++c) ow[c] = ws[wr][((j0 + c) >> 1) - c1];
        store4(wout, i, j0, ow);
        float4 uu = *reinterpret_cast<float4*>(un + (size_t)i * NN + j0);
        float4 vv = *reinterpret_cast<float4*>(vn + (size_t)i * NN + j0);
        float ou[4] = {uu.x, uu.y, uu.z, uu.w};
        float ov[4] = {vv.x, vv.y, vv.z, vv.w};
        int iu = (i > 0 ? i - 1 : 0) - (ib - 1);
        int idn = (i < NN - 1 ? i + 1 : NN - 1) - (ib - 1);
#pragma unroll
        for (int c = 0; c < 4; ++c) {
            int j = j0 + c;
            int jl = (j > 0 ? j - 1 : 0) - (jb - 1);
            int jr = (j < NN - 1 ? j + 1 : NN - 1) - (jb - 1);
            int lcc = j - (jb - 1);
            ou[c] -= 0.5f * (pnew[lr][jr] - pnew[lr][jl]) * DT;
            ov[c] -= 0.5f * (pnew[idn][lcc] - pnew[iu][lcc]) * DT;
        }
        store4(un, i, j0, ou);
        store4(vn, i, j0, ov);
    } else {
        // next residual on p_new + restrict: 4x64 coarse-1024 points, 1/thread
        int cr = tid >> 6, cc = tid & 63;
        float q = 0.f;
#pragma unroll
        for (int dr = 0; dr < 2; ++dr) {
#pragma unroll
            for (int dc = 0; dc < 2; ++dc) {
                int i2 = ib + 2 * cr + dr, j2 = jb + 2 * cc + dc;
                int lr2 = i2 - (ib - 1), lc2 = j2 - (jb - 1);
                int iu2 = (i2 > 0 ? i2 - 1 : 0) - (ib - 1);
                int id2 = (i2 < NN - 1 ? i2 + 1 : NN - 1) - (ib - 1);
                int jl2 = (j2 > 0 ? j2 - 1 : 0) - (jb - 1);
                int jr2 = (j2 < NN - 1 ? j2 + 1 : NN - 1) - (jb - 1);
                q += pnew[iu2][lc2] + pnew[id2][lc2] + pnew[lr2][jl2] + pnew[lr2][jr2]
                   - 4.f * pnew[lr2][lc2] - b[(size_t)i2 * NN + j2];
            }
        }
        q *= 0.25f;
        sq[cr][cc] = q;
        o1024[(size_t)(ib / 2 + cr) * 1024 + jb / 2 + cc] = q;
        __syncthreads();
        if (tid < 64) {
            int rr = tid >> 5, c5 = tid & 31;
            float m = 0.25f * (sq[2 * rr][2 * c5] + sq[2 * rr][2 * c5 + 1] +
                               sq[2 * rr + 1][2 * c5] + sq[2 * rr + 1][2 * c5 + 1]);
            o512[(size_t)(ib / 4 + rr) * 512 + jb / 4 + c5] = m;
            red[rr][c5] = m;
        }
        __syncthreads();
        if (tid < 16) {
            float m = 0.25f * (red[0][2 * tid] + red[0][2 * tid + 1] +
                               red[1][2 * tid] + red[1][2 * tid + 1]);
            o256[(size_t)(ib / 8) * 256 + jb / 8 + tid] = m;
        }
    }
}

extern "C" void kernel_launch(void* const* d_in, const int* in_sizes, int n_in,
                              void* d_out, int out_size, void* d_ws, size_t ws_size,
                              hipStream_t stream) {
    const float* u  = (const float*)d_in[0];
    const float* v  = (const float*)d_in[1];
    const float* p  = (const float*)d_in[2];
    const float* Fx = (const float*)d_in[3];
    const float* Fy = (const float*)d_in[4];
    const float* k1 = (const float*)d_in[5];

    float* out = (float*)d_out;
    float* out_u = out;
    float* out_v = out + (size_t)NN2;
    float* out_p = out + 2 * (size_t)NN2;
    float* out_w = out + 3 * (size_t)NN2;
    float* out_r = out + 4 * (size_t)NN2;

    float* wsb = (float*)d_ws;
    float* b  = wsb;
    float* pA = wsb + (size_t)NN2;
    float* pB = wsb + 2 * (size_t)NN2;
    float* base = wsb + 3 * (size_t)NN2;
    float* rA1024 = base;
    float* rA512  = rA1024 + 1024 * 1024;
    float* rA256  = rA512 + 512 * 512;
    float* rB1024 = rA256 + 256 * 256;
    float* rB512  = rB1024 + 1024 * 1024;
    float* rB256  = rB512 + 512 * 512;
    float* r128   = rB256 + 256 * 256;
    float* w128   = r128 + 128 * 128;
    float* w512   = w128 + 128 * 128;

    // b_u/b_v live in not-yet-needed output regions
    float* bu = out_w;
    float* bv = out_p;

    dim3 blkT(16, 16);
    dim3 gT(32, 128);       // 64x16 tiles
    dim3 blkR(64, 4);
    dim3 gR(8, 128);        // rhs_res: 256x16 fine tiles
    dim3 blkP(32, 8);
    dim3 gP(16, 256);       // pupd3: 128x8 fine tiles
    dim3 gL(2, 128);        // prolong2

    // momentum
    k_pred_f<<<gT, blkT, 0, stream>>>(u, v, k1, p, bu, bv);
    k_corr_f<<<gT, blkT, 0, stream>>>(u, v, k1, p, bu, bv, Fx, Fy, out_u, out_v);
    // b + initial residual pyramid (A)
    k_rhs_res<<<gR, blkR, 0, stream>>>(out_u, out_v, p, b, rA1024, rA512, rA256);

    const float* pcur = p;
    for (int it = 0; it < 5; ++it) {
        const bool useA = (it % 2 == 0);
        const float* R1024 = useA ? rA1024 : rB1024;
        const float* R512  = useA ? rA512  : rB512;
        const float* R256  = useA ? rA256  : rB256;
        float* O1024 = useA ? rB1024 : rA1024;
        float* O512  = useA ? rB512  : rA512;
        float* O256  = useA ? rB256  : rA256;

        k_small2<<<1, 1024, 0, stream>>>(R256, r128, w128, out_r);
        k_prolong2<<<gL, blkR, 0, stream>>>(w128, r128, R256, w512);
        if (it < 4) {
            float* pdst = (it & 1) ? pB : pA;
            k_pupd3<false><<<gP, blkP, 0, stream>>>(pcur, b, w512, R512, R1024,
                                                    pdst, O1024, O512, O256,
                                                    nullptr, nullptr, nullptr);
            pcur = pdst;
        } else {
            k_pupd3<true><<<gP, blkP, 0, stream>>>(pcur, b, w512, R512, R1024,
                                                   out_p, nullptr, nullptr, nullptr,
                                                   out_w, out_u, out_v);
        }
    }
}